// Round 10
// baseline (157.838 us; speedup 1.0000x reference)
//
#include <hip/hip_runtime.h>
#include <math.h>

#define DD 64
#define NN 512
#define LL 1024
#define EPSF 1e-5f
#define NCH 32   // n-chunks (xbar partials per l)

typedef short short8 __attribute__((ext_vector_type(8)));
typedef float f32x4 __attribute__((ext_vector_type(4)));

static __device__ __forceinline__ unsigned bf16_rne(float f) {
  unsigned u = __float_as_uint(f);
  return (u + 0x7FFFu + ((u >> 16) & 1u)) >> 16;
}
static __device__ __forceinline__ float bf16_hi_f(float f) {
  unsigned u = __float_as_uint(f);
  return __uint_as_float((u + 0x7FFFu + ((u >> 16) & 1u)) & 0xFFFF0000u);
}
// HW packed convert: [bf16(a) | bf16(b)<<16]
static __device__ __forceinline__ unsigned cvt_pk_bf16(float a, float b) {
  unsigned r;
  asm("v_cvt_pk_bf16_f32 %0, %1, %2" : "=v"(r) : "v"(a), "v"(b));
  return r;
}

// ---------------------------------------------------------------------------
// Kernel W: pack Wg/Wout into MFMA B-fragment order, split bf16 hi/lo.
// Bpk short8-frag index: ((mv*2 + h)*8 + ct*2 + kt)*64 + lane
// element: col = ct*16 + (lane&15); k = kt*32 + (lane>>4)*8 + e
// ---------------------------------------------------------------------------
__global__ __launch_bounds__(256) void kW(const float* __restrict__ Wg,
                                          const float* __restrict__ Wout,
                                          unsigned* __restrict__ Bpk)
{
  const int idx = blockIdx.x * 256 + threadIdx.x;   // 0..8191
  const int e2   = idx & 3;
  const int lane = (idx >> 2) & 63;
  const int ctkt = (idx >> 8) & 7;
  const int h    = (idx >> 11) & 1;
  const int mv   = (idx >> 12) & 1;
  const int col  = ((ctkt >> 1) << 4) | (lane & 15);
  const int k0   = ((ctkt & 1) << 5) + ((lane >> 4) << 3) + (e2 << 1);
  const float* W = mv ? Wout : Wg;
  const float w0 = W[k0 * DD + col];
  const float w1 = W[(k0 + 1) * DD + col];
  unsigned b0, b1;
  if (h == 0) { b0 = bf16_rne(w0); b1 = bf16_rne(w1); }
  else        { b0 = bf16_rne(w0 - bf16_hi_f(w0)); b1 = bf16_rne(w1 - bf16_hi_f(w1)); }
  Bpk[idx] = b0 | (b1 << 16);
}

// ---------------------------------------------------------------------------
// Kernel A v4 (two-pass streaming, chunked butterfly -> bounded live set):
// pass A: stats only (retain nothing). memory-clobber fence. pass B: per
// 16-d chunk: reload (L2-hot) -> xn -> k/v FMAs -> xnh store -> chunk
// butterfly into P[16]. No 64-float liveness anywhere.
// ---------------------------------------------------------------------------
__global__ __launch_bounds__(256, 4) void kA(
    const float* __restrict__ msa, const float* __restrict__ lnw, const float* __restrict__ lnb,
    const float* __restrict__ Wk, const float* __restrict__ Wv,
    float* __restrict__ kb, float* __restrict__ vb, float* __restrict__ xbarP,
    unsigned short* __restrict__ xnh)
{
  __shared__ float xc[4][16][68];
  const int t = threadIdx.x;
  const int lane = t & 63;
  const int w = t >> 6;
  const int l_loc = t & 15;
  const int n_loc = t >> 4;
  const int lt = blockIdx.x & 63;
  const int nc = blockIdx.x >> 6;
  const int l0 = lt * 16;
  const int n = nc * 16 + n_loc;
  const int l = l0 + l_loc;

  const float4* rp = (const float4*)(msa + ((size_t)n * LL + l) * DD);

  // ---- pass A: LN stats, retain nothing ----
  float s = 0.f, s2 = 0.f;
#pragma unroll
  for (int i = 0; i < 16; ++i) {
    const float4 f = rp[i];
    s += (f.x + f.y) + (f.z + f.w);
    s2 = fmaf(f.x, f.x, s2); s2 = fmaf(f.y, f.y, s2);
    s2 = fmaf(f.z, f.z, s2); s2 = fmaf(f.w, f.w, s2);
  }
  const float mu = s * (1.f / DD);
  const float rs = rsqrtf(fmaf(-mu, mu, s2 * (1.f / DD)) + EPSF);
  const float aa = rs, bb = -mu * rs;

  asm volatile("" ::: "memory");   // force pass-B reloads (no 64-reg row)

  // ---- pass B: chunked xn / proj / xnh / butterfly ----
  float ka[8], va[8], P[16];
#pragma unroll
  for (int j = 0; j < 8; ++j) { ka[j] = 0.f; va[j] = 0.f; }

  uint4* xp = (uint4*)(xnh + ((size_t)n * LL + l) * DD);
#pragma unroll
  for (int c = 0; c < 4; ++c) {
    float x16[16];
#pragma unroll
    for (int i = 0; i < 4; ++i) {
      const float4 f = rp[c * 4 + i];
      const int d = c * 16 + 4 * i;
      x16[4*i+0] = fmaf(fmaf(f.x, aa, bb), lnw[d+0], lnb[d+0]);
      x16[4*i+1] = fmaf(fmaf(f.y, aa, bb), lnw[d+1], lnb[d+1]);
      x16[4*i+2] = fmaf(fmaf(f.z, aa, bb), lnw[d+2], lnb[d+2]);
      x16[4*i+3] = fmaf(fmaf(f.w, aa, bb), lnw[d+3], lnb[d+3]);
    }
#pragma unroll
    for (int e = 0; e < 16; ++e) {
      const int d = c * 16 + e;
#pragma unroll
      for (int j = 0; j < 8; ++j) {
        ka[j] = fmaf(x16[e], Wk[d * 8 + j], ka[j]);
        va[j] = fmaf(x16[e], Wv[d * 8 + j], va[j]);
      }
    }
    {
      uint4 q0, q1;
      q0.x = cvt_pk_bf16(x16[0],  x16[1]);  q0.y = cvt_pk_bf16(x16[2],  x16[3]);
      q0.z = cvt_pk_bf16(x16[4],  x16[5]);  q0.w = cvt_pk_bf16(x16[6],  x16[7]);
      q1.x = cvt_pk_bf16(x16[8],  x16[9]);  q1.y = cvt_pk_bf16(x16[10], x16[11]);
      q1.z = cvt_pk_bf16(x16[12], x16[13]); q1.w = cvt_pk_bf16(x16[14], x16[15]);
      xp[2 * c + 0] = q0;
      xp[2 * c + 1] = q1;
    }
    // chunk butterfly over the 4 same-l lanes: 16 -> 8 -> 4
    {
      const bool hi1 = (lane & 16) != 0;
      float y8[8];
#pragma unroll
      for (int k = 0; k < 8; ++k) {
        const float keep = hi1 ? x16[k + 8] : x16[k];
        const float send = hi1 ? x16[k] : x16[k + 8];
        y8[k] = keep + __shfl_xor(send, 16);
      }
      const bool hi2 = (lane & 32) != 0;
#pragma unroll
      for (int k = 0; k < 4; ++k) {
        const float keep = hi2 ? y8[k + 4] : y8[k];
        const float send = hi2 ? y8[k] : y8[k + 4];
        P[c * 4 + k] = keep + __shfl_xor(send, 32);
      }
    }
  }

  // k/v store: per instr 16 x 128B aligned contiguous chunks
  {
    float4* kp = (float4*)(kb + ((size_t)l * NN + n) * 8);
    float4* vp = (float4*)(vb + ((size_t)l * NN + n) * 8);
    kp[0] = make_float4(ka[0], ka[1], ka[2], ka[3]);
    kp[1] = make_float4(ka[4], ka[5], ka[6], ka[7]);
    vp[0] = make_float4(va[0], va[1], va[2], va[3]);
    vp[1] = make_float4(va[4], va[5], va[6], va[7]);
  }

  // per-chunk d-offset of this lane's 4 partial sums
  const int off = 8 * ((lane >> 4) & 1) + 4 * (lane >> 5);
#pragma unroll
  for (int c = 0; c < 4; ++c)
#pragma unroll
    for (int k = 0; k < 4; ++k)
      xc[w][l_loc][c * 16 + off + k] = P[c * 4 + k];
  __syncthreads();

#pragma unroll
  for (int j = 0; j < 4; ++j) {
    const int c = t * 4 + j;
    const int ll = c >> 6, d = c & 63;
    const float sv = xc[0][ll][d] + xc[1][ll][d] + xc[2][ll][d] + xc[3][ll][d];
    xbarP[((size_t)(l0 + ll) * NCH + nc) * DD + d] = sv;
  }
}

// ---------------------------------------------------------------------------
// Kernel B: unchanged (writes obT[d][l]).
// ---------------------------------------------------------------------------
__global__ __launch_bounds__(512) void kB(
    const float* __restrict__ kb, const float* __restrict__ vb,
    const float* __restrict__ xbarP, const float* __restrict__ Wq,
    float* __restrict__ obT)
{
  __shared__ float xbL[DD];
  __shared__ float qs[DD];
  __shared__ float ks[NN * 9];
  __shared__ float vs[NN * 9];
  const int l = blockIdx.x;
  const int t = threadIdx.x;
  const int h = t >> 6;
  const int lane = t & 63;

  const float* kl = kb + (size_t)l * NN * 8;
  const float* vl = vb + (size_t)l * NN * 8;
#pragma unroll
  for (int i = 0; i < 8; ++i) {
    const int idx = i * 512 + t;
    const int n = idx >> 3, j = idx & 7;
    ks[n*9 + j] = kl[idx];
    vs[n*9 + j] = vl[idx];
  }
  if (t < DD) {
    float s = 0.f;
    for (int p = 0; p < NCH; ++p) s += xbarP[((size_t)l * NCH + p) * DD + t];
    xbL[t] = s * (1.f / NN);
  }
  __syncthreads();
  if (t < DD) {
    float acc = 0.f;
    for (int d = 0; d < DD; ++d) acc = fmaf(xbL[d], Wq[d*DD + t], acc);
    qs[t] = acc * 0.35355339059327373f;
  }
  __syncthreads();

  float sc[8];
  float m = -1e30f;
#pragma unroll
  for (int i = 0; i < 8; ++i) {
    const int n = i * 64 + lane;
    float s = 0.f;
#pragma unroll
    for (int d = 0; d < 8; ++d) s = fmaf(qs[h*8 + d], ks[n*9 + d], s);
    sc[i] = s;
    m = fmaxf(m, s);
  }
#pragma unroll
  for (int off = 32; off; off >>= 1) m = fmaxf(m, __shfl_xor(m, off));
  float ssum = 0.f;
#pragma unroll
  for (int i = 0; i < 8; ++i) { sc[i] = __expf(sc[i] - m); ssum += sc[i]; }
#pragma unroll
  for (int off = 32; off; off >>= 1) ssum += __shfl_xor(ssum, off);
  const float inv = 1.f / ssum;

  float oacc[8];
#pragma unroll
  for (int d = 0; d < 8; ++d) oacc[d] = 0.f;
#pragma unroll
  for (int i = 0; i < 8; ++i) {
    const int n = i * 64 + lane;
#pragma unroll
    for (int d = 0; d < 8; ++d) oacc[d] = fmaf(sc[i], vs[n*9 + d], oacc[d]);
  }
#pragma unroll
  for (int d = 0; d < 8; ++d) {
#pragma unroll
    for (int off = 32; off; off >>= 1) oacc[d] += __shfl_xor(oacc[d], off);
  }
  if (lane == 0) {
#pragma unroll
    for (int d = 0; d < 8; ++d)
      obT[(size_t)(h * 8 + d) * LL + l] = oacc[d] * inv;
  }
}

// ---------------------------------------------------------------------------
// Kernel C v5: unchanged from R8/R9. mv1 A-frags direct from global xnh,
// 2-term mv1; sigmoid*o -> t hi/lo -> wave-private LDS -> 3-term mv2.
// Zero barriers.
// ---------------------------------------------------------------------------
__global__ __launch_bounds__(256, 4) void kC(
    const unsigned short* __restrict__ xnh, const unsigned* __restrict__ Bpk,
    const float* __restrict__ bg, const float* __restrict__ obT,
    const float* __restrict__ bout, float* __restrict__ out)
{
  __shared__ unsigned short TH[128 * 72];  // 18 KB (t hi)
  __shared__ unsigned short TL[128 * 72];  // 18 KB (t lo)
  const int t = threadIdx.x;
  const int lane = t & 63;
  const int w = t >> 6;
  const int rbase = 32 * w;
  const size_t R0 = (size_t)blockIdx.x * 128;

  const short8* Bp = (const short8*)Bpk;   // frag*64 + lane

  f32x4 acc[2][4];
#pragma unroll
  for (int rt = 0; rt < 2; ++rt)
#pragma unroll
    for (int ct = 0; ct < 4; ++ct) acc[rt][ct] = f32x4{0.f, 0.f, 0.f, 0.f};

  {
    short8 ah[2][2];
#pragma unroll
    for (int rt = 0; rt < 2; ++rt) {
      const size_t ar = R0 + rbase + rt * 16 + (lane & 15);
      const int kg = (lane >> 4) * 8;
      ah[rt][0] = *(const short8*)&xnh[ar * DD + kg];
      ah[rt][1] = *(const short8*)&xnh[ar * DD + 32 + kg];
    }
#pragma unroll
    for (int ct = 0; ct < 4; ++ct) {
      const short8 bh0 = Bp[(0 * 8 + ct * 2 + 0) * 64 + lane];
      const short8 bh1 = Bp[(0 * 8 + ct * 2 + 1) * 64 + lane];
      const short8 bl0 = Bp[(1 * 8 + ct * 2 + 0) * 64 + lane];
      const short8 bl1 = Bp[(1 * 8 + ct * 2 + 1) * 64 + lane];
#pragma unroll
      for (int rt = 0; rt < 2; ++rt) {
        f32x4 c = acc[rt][ct];
        c = __builtin_amdgcn_mfma_f32_16x16x32_bf16(ah[rt][0], bh0, c, 0, 0, 0);
        c = __builtin_amdgcn_mfma_f32_16x16x32_bf16(ah[rt][1], bh1, c, 0, 0, 0);
        c = __builtin_amdgcn_mfma_f32_16x16x32_bf16(ah[rt][0], bl0, c, 0, 0, 0);
        c = __builtin_amdgcn_mfma_f32_16x16x32_bf16(ah[rt][1], bl1, c, 0, 0, 0);
        acc[rt][ct] = c;
      }
    }
  }

#pragma unroll
  for (int rt = 0; rt < 2; ++rt) {
    const int rl0 = rbase + rt * 16 + ((lane >> 4) << 2);
    const int li0 = (int)((R0 + rl0) & (LL - 1));
#pragma unroll
    for (int ct = 0; ct < 4; ++ct) {
      const int col = ct * 16 + (lane & 15);
      const float4 ov = *(const float4*)&obT[(size_t)col * LL + li0];
      const float bgc = bg[col];
      const float p0 = acc[rt][ct][0] + bgc;
      const float p1 = acc[rt][ct][1] + bgc;
      const float p2 = acc[rt][ct][2] + bgc;
      const float p3 = acc[rt][ct][3] + bgc;
      const float tv0 = ov.x / (1.f + __expf(-p0));
      const float tv1 = ov.y / (1.f + __expf(-p1));
      const float tv2 = ov.z / (1.f + __expf(-p2));
      const float tv3 = ov.w / (1.f + __expf(-p3));
      const unsigned ph01 = cvt_pk_bf16(tv0, tv1);
      const unsigned ph23 = cvt_pk_bf16(tv2, tv3);
      const float h0 = __uint_as_float(ph01 << 16);
      const float h1 = __uint_as_float(ph01 & 0xFFFF0000u);
      const float h2 = __uint_as_float(ph23 << 16);
      const float h3 = __uint_as_float(ph23 & 0xFFFF0000u);
      const unsigned pl01 = cvt_pk_bf16(tv0 - h0, tv1 - h1);
      const unsigned pl23 = cvt_pk_bf16(tv2 - h2, tv3 - h3);
      TH[(rl0 + 0) * 72 + col] = (unsigned short)ph01;
      TH[(rl0 + 1) * 72 + col] = (unsigned short)(ph01 >> 16);
      TH[(rl0 + 2) * 72 + col] = (unsigned short)ph23;
      TH[(rl0 + 3) * 72 + col] = (unsigned short)(ph23 >> 16);
      TL[(rl0 + 0) * 72 + col] = (unsigned short)pl01;
      TL[(rl0 + 1) * 72 + col] = (unsigned short)(pl01 >> 16);
      TL[(rl0 + 2) * 72 + col] = (unsigned short)pl23;
      TL[(rl0 + 3) * 72 + col] = (unsigned short)(pl23 >> 16);
    }
  }
  // no barrier: wave-private rows

#pragma unroll
  for (int rt = 0; rt < 2; ++rt)
#pragma unroll
    for (int ct = 0; ct < 4; ++ct) {
      const float bo = bout[ct * 16 + (lane & 15)];
      acc[rt][ct] = f32x4{bo, bo, bo, bo};
    }
  {
    short8 ah[2][2], al[2][2];
#pragma unroll
    for (int rt = 0; rt < 2; ++rt) {
      const int ar = rbase + rt * 16 + (lane & 15);
      const int kg = (lane >> 4) * 8;
      ah[rt][0] = *(const short8*)&TH[ar * 72 + kg];
      ah[rt][1] = *(const short8*)&TH[ar * 72 + 32 + kg];
      al[rt][0] = *(const short8*)&TL[ar * 72 + kg];
      al[rt][1] = *(const short8*)&TL[ar * 72 + 32 + kg];
    }
#pragma unroll
    for (int ct = 0; ct < 4; ++ct) {
      const short8 bh0 = Bp[(2 * 8 + ct * 2 + 0) * 64 + lane];
      const short8 bh1 = Bp[(2 * 8 + ct * 2 + 1) * 64 + lane];
      const short8 bl0 = Bp[(3 * 8 + ct * 2 + 0) * 64 + lane];
      const short8 bl1 = Bp[(3 * 8 + ct * 2 + 1) * 64 + lane];
#pragma unroll
      for (int rt = 0; rt < 2; ++rt) {
        f32x4 c = acc[rt][ct];
        c = __builtin_amdgcn_mfma_f32_16x16x32_bf16(ah[rt][0], bh0, c, 0, 0, 0);
        c = __builtin_amdgcn_mfma_f32_16x16x32_bf16(ah[rt][1], bh1, c, 0, 0, 0);
        c = __builtin_amdgcn_mfma_f32_16x16x32_bf16(ah[rt][0], bl0, c, 0, 0, 0);
        c = __builtin_amdgcn_mfma_f32_16x16x32_bf16(ah[rt][1], bl1, c, 0, 0, 0);
        c = __builtin_amdgcn_mfma_f32_16x16x32_bf16(al[rt][0], bh0, c, 0, 0, 0);
        c = __builtin_amdgcn_mfma_f32_16x16x32_bf16(al[rt][1], bh1, c, 0, 0, 0);
        acc[rt][ct] = c;
      }
    }
  }

#pragma unroll
  for (int rt = 0; rt < 2; ++rt) {
#pragma unroll
    for (int j = 0; j < 4; ++j) {
      const size_t rg = R0 + rbase + rt * 16 + ((lane >> 4) << 2) + j;
#pragma unroll
      for (int ct = 0; ct < 4; ++ct)
        out[rg * DD + ct * 16 + (lane & 15)] = acc[rt][ct][j];
    }
  }
}

// ---------------------------------------------------------------------------
extern "C" void kernel_launch(void* const* d_in, const int* in_sizes, int n_in,
                              void* d_out, int out_size, void* d_ws, size_t ws_size,
                              hipStream_t stream)
{
  const float* msa  = (const float*)d_in[0];
  const float* lnw  = (const float*)d_in[1];
  const float* lnb  = (const float*)d_in[2];
  const float* Wq   = (const float*)d_in[3];
  const float* Wk   = (const float*)d_in[4];
  const float* Wv   = (const float*)d_in[5];
  const float* Wg   = (const float*)d_in[6];
  const float* bg   = (const float*)d_in[7];
  const float* Wout = (const float*)d_in[8];
  const float* bout = (const float*)d_in[9];
  float* out = (float*)d_out;

  float* kb    = (float*)d_ws;                        // (L, N, 8)  16 MB
  float* vb    = kb + (size_t)LL * NN * 8;            // (L, N, 8)  16 MB
  float* xbarP = vb + (size_t)LL * NN * 8;            // (L, 32, 64) 8 MB
  float* obT   = xbarP + (size_t)LL * NCH * DD;       // (64, L)   256 KB
  unsigned* Bpk = (unsigned*)(obT + (size_t)DD * LL); // 32 KB packed weights
  unsigned short* xnh = (unsigned short*)(Bpk + 8192);// (N*L, 64) bf16 64 MB

  kW<<<32, 256, 0, stream>>>(Wg, Wout, Bpk);
  kA<<<64 * NCH, 256, 0, stream>>>(msa, lnw, lnb, Wk, Wv, kb, vb, xbarP, xnh);
  kB<<<LL, 512, 0, stream>>>(kb, vb, xbarP, Wq, obT);
  kC<<<(NN * LL) / 128, 256, 0, stream>>>(xnh, Bpk, bg, obT, bout, out);
}

// Round 11
// 128.359 us; speedup vs baseline: 1.2297x; 1.2297x over previous
//
#include <hip/hip_runtime.h>
#include <math.h>

#define DD 64
#define NN 512
#define LL 1024
#define EPSF 1e-5f
#define NCH 32   // n-chunks (xbar partials per l)

typedef short short8 __attribute__((ext_vector_type(8)));
typedef float f32x4 __attribute__((ext_vector_type(4)));

// pure-C round-to-nearest-even bf16 (bits in low 16) — NO inline asm
static __device__ __forceinline__ unsigned bf16_rne(float f) {
  unsigned u = __float_as_uint(f);
  return (u + 0x7FFFu + ((u >> 16) & 1u)) >> 16;
}
static __device__ __forceinline__ float bf16_hi_f(float f) {
  unsigned u = __float_as_uint(f);
  return __uint_as_float((u + 0x7FFFu + ((u >> 16) & 1u)) & 0xFFFF0000u);
}

// ---------------------------------------------------------------------------
// Kernel W: pack Wg/Wout into MFMA B-fragment order, split bf16 hi/lo.
// Bpk short8-frag index: ((mv*2 + h)*8 + ct*2 + kt)*64 + lane
// element: col = ct*16 + (lane&15); k = kt*32 + (lane>>4)*8 + e
// ---------------------------------------------------------------------------
__global__ __launch_bounds__(256) void kW(const float* __restrict__ Wg,
                                          const float* __restrict__ Wout,
                                          unsigned* __restrict__ Bpk)
{
  const int idx = blockIdx.x * 256 + threadIdx.x;   // 0..8191
  const int e2   = idx & 3;
  const int lane = (idx >> 2) & 63;
  const int ctkt = (idx >> 8) & 7;
  const int h    = (idx >> 11) & 1;
  const int mv   = (idx >> 12) & 1;
  const int col  = ((ctkt >> 1) << 4) | (lane & 15);
  const int k0   = ((ctkt & 1) << 5) + ((lane >> 4) << 3) + (e2 << 1);
  const float* W = mv ? Wout : Wg;
  const float w0 = W[k0 * DD + col];
  const float w1 = W[(k0 + 1) * DD + col];
  unsigned b0, b1;
  if (h == 0) { b0 = bf16_rne(w0); b1 = bf16_rne(w1); }
  else        { b0 = bf16_rne(w0 - bf16_hi_f(w0)); b1 = bf16_rne(w1 - bf16_hi_f(w1)); }
  Bpk[idx] = b0 | (b1 << 16);
}

// ---------------------------------------------------------------------------
// Kernel A v5 (R7-proven single-pass + pure-C RNE + coalesced xnh layout):
// block = 16 l x 16 n rows; thread = one row in regs (X[64]); LN stats ->
// fused d-loop {xn, k/v FMAs, per-8d-group pack -> xnh[n][g][l][8] store
// (256B coalesced across 16 consecutive-l lanes)}; k/v store; butterfly ->
// xbar partial.
// ---------------------------------------------------------------------------
__global__ __launch_bounds__(256, 4) void kA(
    const float* __restrict__ msa, const float* __restrict__ lnw, const float* __restrict__ lnb,
    const float* __restrict__ Wk, const float* __restrict__ Wv,
    float* __restrict__ kb, float* __restrict__ vb, float* __restrict__ xbarP,
    unsigned short* __restrict__ xnh)
{
  __shared__ float xc[4][16][68];
  const int t = threadIdx.x;
  const int lane = t & 63;
  const int w = t >> 6;
  const int l_loc = t & 15;
  const int n_loc = t >> 4;
  const int lt = blockIdx.x & 63;
  const int nc = blockIdx.x >> 6;
  const int l0 = lt * 16;
  const int n = nc * 16 + n_loc;
  const int l = l0 + l_loc;

  float X[DD];
  {
    const float4* rp = (const float4*)(msa + ((size_t)n * LL + l) * DD);
#pragma unroll
    for (int i = 0; i < 16; ++i) {
      const float4 f = rp[i];
      X[4*i+0] = f.x; X[4*i+1] = f.y; X[4*i+2] = f.z; X[4*i+3] = f.w;
    }
  }

  float s = 0.f, s2 = 0.f;
#pragma unroll
  for (int d = 0; d < DD; ++d) { s += X[d]; s2 = fmaf(X[d], X[d], s2); }
  const float mu = s * (1.f / DD);
  const float rs = rsqrtf(fmaf(-mu, mu, s2 * (1.f / DD)) + EPSF);
  const float aa = rs, bb = -mu * rs;

  float ka[8], va[8];
#pragma unroll
  for (int j = 0; j < 8; ++j) { ka[j] = 0.f; va[j] = 0.f; }

  uint4* xg = (uint4*)xnh;   // [n*8+g][l] of 8-bf16 groups
#pragma unroll
  for (int g = 0; g < 8; ++g) {
#pragma unroll
    for (int e = 0; e < 8; ++e) {
      const int d = 8 * g + e;
      const float xn = fmaf(fmaf(X[d], aa, bb), lnw[d], lnb[d]);
      X[d] = xn;
#pragma unroll
      for (int j = 0; j < 8; ++j) {
        ka[j] = fmaf(xn, Wk[d * 8 + j], ka[j]);
        va[j] = fmaf(xn, Wv[d * 8 + j], va[j]);
      }
    }
    uint4 q;
    q.x = bf16_rne(X[8*g+0]) | (bf16_rne(X[8*g+1]) << 16);
    q.y = bf16_rne(X[8*g+2]) | (bf16_rne(X[8*g+3]) << 16);
    q.z = bf16_rne(X[8*g+4]) | (bf16_rne(X[8*g+5]) << 16);
    q.w = bf16_rne(X[8*g+6]) | (bf16_rne(X[8*g+7]) << 16);
    xg[(size_t)(n * 8 + g) * LL + l] = q;   // 256B coalesced per 16-lane group
  }

  {
    float4* kp = (float4*)(kb + ((size_t)l * NN + n) * 8);
    float4* vp = (float4*)(vb + ((size_t)l * NN + n) * 8);
    kp[0] = make_float4(ka[0], ka[1], ka[2], ka[3]);
    kp[1] = make_float4(ka[4], ka[5], ka[6], ka[7]);
    vp[0] = make_float4(va[0], va[1], va[2], va[3]);
    vp[1] = make_float4(va[4], va[5], va[6], va[7]);
  }

  {
    const bool hi1 = (lane & 16) != 0;
#pragma unroll
    for (int k = 0; k < 32; ++k) {
      const float keep = hi1 ? X[k + 32] : X[k];
      const float send = hi1 ? X[k] : X[k + 32];
      X[k] = keep + __shfl_xor(send, 16);
    }
    const bool hi2 = (lane & 32) != 0;
#pragma unroll
    for (int k = 0; k < 16; ++k) {
      const float keep = hi2 ? X[k + 16] : X[k];
      const float send = hi2 ? X[k] : X[k + 16];
      X[k] = keep + __shfl_xor(send, 32);
    }
  }
  const int d0i = ((lane >> 4) & 1) * 32 + (lane >> 5) * 16;
#pragma unroll
  for (int k = 0; k < 16; ++k) xc[w][l_loc][d0i + k] = X[k];
  __syncthreads();

#pragma unroll
  for (int j = 0; j < 4; ++j) {
    const int c = t * 4 + j;
    const int ll = c >> 6, d = c & 63;
    const float sv = xc[0][ll][d] + xc[1][ll][d] + xc[2][ll][d] + xc[3][ll][d];
    xbarP[((size_t)(l0 + ll) * NCH + nc) * DD + d] = sv;
  }
}

// ---------------------------------------------------------------------------
// Kernel B: unchanged (writes obT[d][l]).
// ---------------------------------------------------------------------------
__global__ __launch_bounds__(512) void kB(
    const float* __restrict__ kb, const float* __restrict__ vb,
    const float* __restrict__ xbarP, const float* __restrict__ Wq,
    float* __restrict__ obT)
{
  __shared__ float xbL[DD];
  __shared__ float qs[DD];
  __shared__ float ks[NN * 9];
  __shared__ float vs[NN * 9];
  const int l = blockIdx.x;
  const int t = threadIdx.x;
  const int h = t >> 6;
  const int lane = t & 63;

  const float* kl = kb + (size_t)l * NN * 8;
  const float* vl = vb + (size_t)l * NN * 8;
#pragma unroll
  for (int i = 0; i < 8; ++i) {
    const int idx = i * 512 + t;
    const int n = idx >> 3, j = idx & 7;
    ks[n*9 + j] = kl[idx];
    vs[n*9 + j] = vl[idx];
  }
  if (t < DD) {
    float s = 0.f;
    for (int p = 0; p < NCH; ++p) s += xbarP[((size_t)l * NCH + p) * DD + t];
    xbL[t] = s * (1.f / NN);
  }
  __syncthreads();
  if (t < DD) {
    float acc = 0.f;
    for (int d = 0; d < DD; ++d) acc = fmaf(xbL[d], Wq[d*DD + t], acc);
    qs[t] = acc * 0.35355339059327373f;
  }
  __syncthreads();

  float sc[8];
  float m = -1e30f;
#pragma unroll
  for (int i = 0; i < 8; ++i) {
    const int n = i * 64 + lane;
    float s = 0.f;
#pragma unroll
    for (int d = 0; d < 8; ++d) s = fmaf(qs[h*8 + d], ks[n*9 + d], s);
    sc[i] = s;
    m = fmaxf(m, s);
  }
#pragma unroll
  for (int off = 32; off; off >>= 1) m = fmaxf(m, __shfl_xor(m, off));
  float ssum = 0.f;
#pragma unroll
  for (int i = 0; i < 8; ++i) { sc[i] = __expf(sc[i] - m); ssum += sc[i]; }
#pragma unroll
  for (int off = 32; off; off >>= 1) ssum += __shfl_xor(ssum, off);
  const float inv = 1.f / ssum;

  float oacc[8];
#pragma unroll
  for (int d = 0; d < 8; ++d) oacc[d] = 0.f;
#pragma unroll
  for (int i = 0; i < 8; ++i) {
    const int n = i * 64 + lane;
#pragma unroll
    for (int d = 0; d < 8; ++d) oacc[d] = fmaf(sc[i], vs[n*9 + d], oacc[d]);
  }
#pragma unroll
  for (int d = 0; d < 8; ++d) {
#pragma unroll
    for (int off = 32; off; off >>= 1) oacc[d] += __shfl_xor(oacc[d], off);
  }
  if (lane == 0) {
#pragma unroll
    for (int d = 0; d < 8; ++d)
      obT[(size_t)(h * 8 + d) * LL + l] = oacc[d] * inv;
  }
}

// ---------------------------------------------------------------------------
// Kernel C v6: as v5 (zero-barrier, direct-global mv1, 2-term mv1 / 3-term
// mv2) but pure-C RNE splits and the [n][g][l][8] xnh layout (256B-contig
// A-frag reads).
// ---------------------------------------------------------------------------
__global__ __launch_bounds__(256, 4) void kC(
    const unsigned short* __restrict__ xnh, const unsigned* __restrict__ Bpk,
    const float* __restrict__ bg, const float* __restrict__ obT,
    const float* __restrict__ bout, float* __restrict__ out)
{
  __shared__ unsigned short TH[128 * 72];  // 18 KB (t hi)
  __shared__ unsigned short TL[128 * 72];  // 18 KB (t lo)
  const int t = threadIdx.x;
  const int lane = t & 63;
  const int w = t >> 6;
  const int rbase = 32 * w;
  const size_t R0 = (size_t)blockIdx.x * 128;
  const int nblk = (int)(R0 >> 10);        // n (128 | 1024 -> constant/block)
  const int lbase = (int)(R0 & (LL - 1));  // l0

  const short8* Bp = (const short8*)Bpk;   // frag*64 + lane
  const short8* Xp = (const short8*)xnh;   // [n*8+g][l]

  f32x4 acc[2][4];
#pragma unroll
  for (int rt = 0; rt < 2; ++rt)
#pragma unroll
    for (int ct = 0; ct < 4; ++ct) acc[rt][ct] = f32x4{0.f, 0.f, 0.f, 0.f};

  {
    short8 ah[2][2];
#pragma unroll
    for (int rt = 0; rt < 2; ++rt) {
      const int ar_l = lbase + rbase + rt * 16 + (lane & 15);
      const int g = lane >> 4;
      ah[rt][0] = Xp[(size_t)(nblk * 8 + g) * LL + ar_l];
      ah[rt][1] = Xp[(size_t)(nblk * 8 + 4 + g) * LL + ar_l];
    }
#pragma unroll
    for (int ct = 0; ct < 4; ++ct) {
      const short8 bh0 = Bp[(0 * 8 + ct * 2 + 0) * 64 + lane];
      const short8 bh1 = Bp[(0 * 8 + ct * 2 + 1) * 64 + lane];
      const short8 bl0 = Bp[(1 * 8 + ct * 2 + 0) * 64 + lane];
      const short8 bl1 = Bp[(1 * 8 + ct * 2 + 1) * 64 + lane];
#pragma unroll
      for (int rt = 0; rt < 2; ++rt) {
        f32x4 c = acc[rt][ct];
        c = __builtin_amdgcn_mfma_f32_16x16x32_bf16(ah[rt][0], bh0, c, 0, 0, 0);
        c = __builtin_amdgcn_mfma_f32_16x16x32_bf16(ah[rt][1], bh1, c, 0, 0, 0);
        c = __builtin_amdgcn_mfma_f32_16x16x32_bf16(ah[rt][0], bl0, c, 0, 0, 0);
        c = __builtin_amdgcn_mfma_f32_16x16x32_bf16(ah[rt][1], bl1, c, 0, 0, 0);
        acc[rt][ct] = c;
      }
    }
  }

  // ---- sigmoid * o -> t, pure-C hi/lo split into TH/TL (wave-private) ----
#pragma unroll
  for (int rt = 0; rt < 2; ++rt) {
    const int rl0 = rbase + rt * 16 + ((lane >> 4) << 2);
    const int li0 = (int)((R0 + rl0) & (LL - 1));
#pragma unroll
    for (int ct = 0; ct < 4; ++ct) {
      const int col = ct * 16 + (lane & 15);
      const float4 ov = *(const float4*)&obT[(size_t)col * LL + li0];
      const float bgc = bg[col];
#define SIG_STORE(j, ocomp)                                             \
      {                                                                 \
        const float pre = acc[rt][ct][j] + bgc;                         \
        const float tv = (ocomp) / (1.f + __expf(-pre));                \
        const unsigned hb = bf16_rne(tv);                               \
        TH[(rl0 + (j)) * 72 + col] = (unsigned short)hb;                \
        const float rvl = tv - __uint_as_float(hb << 16);               \
        TL[(rl0 + (j)) * 72 + col] = (unsigned short)bf16_rne(rvl);     \
      }
      SIG_STORE(0, ov.x) SIG_STORE(1, ov.y) SIG_STORE(2, ov.z) SIG_STORE(3, ov.w)
#undef SIG_STORE
    }
  }
  // no barrier: wave-private rows

  // ---- mv2: out = t @ Wout + bout (3-term) ----
#pragma unroll
  for (int rt = 0; rt < 2; ++rt)
#pragma unroll
    for (int ct = 0; ct < 4; ++ct) {
      const float bo = bout[ct * 16 + (lane & 15)];
      acc[rt][ct] = f32x4{bo, bo, bo, bo};
    }
  {
    short8 ah[2][2], al[2][2];
#pragma unroll
    for (int rt = 0; rt < 2; ++rt) {
      const int ar = rbase + rt * 16 + (lane & 15);
      const int kg = (lane >> 4) * 8;
      ah[rt][0] = *(const short8*)&TH[ar * 72 + kg];
      ah[rt][1] = *(const short8*)&TH[ar * 72 + 32 + kg];
      al[rt][0] = *(const short8*)&TL[ar * 72 + kg];
      al[rt][1] = *(const short8*)&TL[ar * 72 + 32 + kg];
    }
#pragma unroll
    for (int ct = 0; ct < 4; ++ct) {
      const short8 bh0 = Bp[(2 * 8 + ct * 2 + 0) * 64 + lane];
      const short8 bh1 = Bp[(2 * 8 + ct * 2 + 1) * 64 + lane];
      const short8 bl0 = Bp[(3 * 8 + ct * 2 + 0) * 64 + lane];
      const short8 bl1 = Bp[(3 * 8 + ct * 2 + 1) * 64 + lane];
#pragma unroll
      for (int rt = 0; rt < 2; ++rt) {
        f32x4 c = acc[rt][ct];
        c = __builtin_amdgcn_mfma_f32_16x16x32_bf16(ah[rt][0], bh0, c, 0, 0, 0);
        c = __builtin_amdgcn_mfma_f32_16x16x32_bf16(ah[rt][1], bh1, c, 0, 0, 0);
        c = __builtin_amdgcn_mfma_f32_16x16x32_bf16(ah[rt][0], bl0, c, 0, 0, 0);
        c = __builtin_amdgcn_mfma_f32_16x16x32_bf16(ah[rt][1], bl1, c, 0, 0, 0);
        c = __builtin_amdgcn_mfma_f32_16x16x32_bf16(al[rt][0], bh0, c, 0, 0, 0);
        c = __builtin_amdgcn_mfma_f32_16x16x32_bf16(al[rt][1], bh1, c, 0, 0, 0);
        acc[rt][ct] = c;
      }
    }
  }

#pragma unroll
  for (int rt = 0; rt < 2; ++rt) {
#pragma unroll
    for (int j = 0; j < 4; ++j) {
      const size_t rg = R0 + rbase + rt * 16 + ((lane >> 4) << 2) + j;
#pragma unroll
      for (int ct = 0; ct < 4; ++ct)
        out[rg * DD + ct * 16 + (lane & 15)] = acc[rt][ct][j];
    }
  }
}

// ---------------------------------------------------------------------------
extern "C" void kernel_launch(void* const* d_in, const int* in_sizes, int n_in,
                              void* d_out, int out_size, void* d_ws, size_t ws_size,
                              hipStream_t stream)
{
  const float* msa  = (const float*)d_in[0];
  const float* lnw  = (const float*)d_in[1];
  const float* lnb  = (const float*)d_in[2];
  const float* Wq   = (const float*)d_in[3];
  const float* Wk   = (const float*)d_in[4];
  const float* Wv   = (const float*)d_in[5];
  const float* Wg   = (const float*)d_in[6];
  const float* bg   = (const float*)d_in[7];
  const float* Wout = (const float*)d_in[8];
  const float* bout = (const float*)d_in[9];
  float* out = (float*)d_out;

  float* kb    = (float*)d_ws;                        // (L, N, 8)  16 MB
  float* vb    = kb + (size_t)LL * NN * 8;            // (L, N, 8)  16 MB
  float* xbarP = vb + (size_t)LL * NN * 8;            // (L, 32, 64) 8 MB
  float* obT   = xbarP + (size_t)LL * NCH * DD;       // (64, L)   256 KB
  unsigned* Bpk = (unsigned*)(obT + (size_t)DD * LL); // 32 KB packed weights
  unsigned short* xnh = (unsigned short*)(Bpk + 8192);// (N*8, L, 8) bf16 64 MB

  kW<<<32, 256, 0, stream>>>(Wg, Wout, Bpk);
  kA<<<64 * NCH, 256, 0, stream>>>(msa, lnw, lnb, Wk, Wv, kb, vb, xbarP, xnh);
  kB<<<LL, 512, 0, stream>>>(kb, vb, xbarP, Wq, obT);
  kC<<<(NN * LL) / 128, 256, 0, stream>>>(xnh, Bpk, bg, obT, bout, out);
}

// Round 12
// 125.857 us; speedup vs baseline: 1.2541x; 1.0199x over previous
//
#include <hip/hip_runtime.h>
#include <math.h>

#define DD 64
#define NN 512
#define LL 1024
#define EPSF 1e-5f
#define NCH 32   // n-chunks (xbar partials per l)

typedef short short8 __attribute__((ext_vector_type(8)));
typedef float f32x4 __attribute__((ext_vector_type(4)));

// pure-C round-to-nearest-even bf16 (bits in low 16) — NO inline asm
static __device__ __forceinline__ unsigned bf16_rne(float f) {
  unsigned u = __float_as_uint(f);
  return (u + 0x7FFFu + ((u >> 16) & 1u)) >> 16;
}
static __device__ __forceinline__ float bf16_hi_f(float f) {
  unsigned u = __float_as_uint(f);
  return __uint_as_float((u + 0x7FFFu + ((u >> 16) & 1u)) & 0xFFFF0000u);
}
static __device__ __forceinline__ short8 pack8(unsigned a, unsigned b,
                                               unsigned c, unsigned d) {
  union { uint4 u; short8 s; } x;
  x.u = make_uint4(a, b, c, d);
  return x.s;
}

// ---------------------------------------------------------------------------
// Kernel W: pack Wg/Wout into MFMA B-fragment order, split bf16 hi/lo.
// Bpk short8-frag index: ((mv*2 + h)*8 + ct*2 + kt)*64 + lane
// element: col = ct*16 + (lane&15); k = kt*32 + (lane>>4)*8 + e
// ---------------------------------------------------------------------------
__global__ __launch_bounds__(256) void kW(const float* __restrict__ Wg,
                                          const float* __restrict__ Wout,
                                          unsigned* __restrict__ Bpk)
{
  const int idx = blockIdx.x * 256 + threadIdx.x;   // 0..8191
  const int e2   = idx & 3;
  const int lane = (idx >> 2) & 63;
  const int ctkt = (idx >> 8) & 7;
  const int h    = (idx >> 11) & 1;
  const int mv   = (idx >> 12) & 1;
  const int col  = ((ctkt >> 1) << 4) | (lane & 15);
  const int k0   = ((ctkt & 1) << 5) + ((lane >> 4) << 3) + (e2 << 1);
  const float* W = mv ? Wout : Wg;
  const float w0 = W[k0 * DD + col];
  const float w1 = W[(k0 + 1) * DD + col];
  unsigned b0, b1;
  if (h == 0) { b0 = bf16_rne(w0); b1 = bf16_rne(w1); }
  else        { b0 = bf16_rne(w0 - bf16_hi_f(w0)); b1 = bf16_rne(w1 - bf16_hi_f(w1)); }
  Bpk[idx] = b0 | (b1 << 16);
}

// ---------------------------------------------------------------------------
// Kernel A v6 = R5/R7 proven structure (X[64] in regs, fused d-loop, butterfly)
// + ONE 8B stats store per row (aa=rs, bb=-mu*rs). NO xnh phase.
// ---------------------------------------------------------------------------
__global__ __launch_bounds__(256, 4) void kA(
    const float* __restrict__ msa, const float* __restrict__ lnw, const float* __restrict__ lnb,
    const float* __restrict__ Wk, const float* __restrict__ Wv,
    float* __restrict__ kb, float* __restrict__ vb, float* __restrict__ xbarP,
    float* __restrict__ stats)
{
  __shared__ float xc[4][16][68];
  const int t = threadIdx.x;
  const int lane = t & 63;
  const int w = t >> 6;
  const int l_loc = t & 15;
  const int n_loc = t >> 4;
  const int lt = blockIdx.x & 63;
  const int nc = blockIdx.x >> 6;
  const int l0 = lt * 16;
  const int n = nc * 16 + n_loc;
  const int l = l0 + l_loc;

  float X[DD];
  {
    const float4* rp = (const float4*)(msa + ((size_t)n * LL + l) * DD);
#pragma unroll
    for (int i = 0; i < 16; ++i) {
      const float4 f = rp[i];
      X[4*i+0] = f.x; X[4*i+1] = f.y; X[4*i+2] = f.z; X[4*i+3] = f.w;
    }
  }

  float s = 0.f, s2 = 0.f;
#pragma unroll
  for (int d = 0; d < DD; ++d) { s += X[d]; s2 = fmaf(X[d], X[d], s2); }
  const float mu = s * (1.f / DD);
  const float rs = rsqrtf(fmaf(-mu, mu, s2 * (1.f / DD)) + EPSF);

  // publish per-row affine for kC's on-the-fly fragment build
  {
    float2* sp = (float2*)(stats + ((size_t)n * LL + l) * 2);
    *sp = make_float2(rs, -mu * rs);
  }

  float ka[8], va[8];
#pragma unroll
  for (int j = 0; j < 8; ++j) { ka[j] = 0.f; va[j] = 0.f; }
#pragma unroll
  for (int d = 0; d < DD; ++d) {
    const float xn = fmaf((X[d] - mu) * rs, lnw[d], lnb[d]);
    X[d] = xn;
#pragma unroll
    for (int j = 0; j < 8; ++j) {
      ka[j] = fmaf(xn, Wk[d * 8 + j], ka[j]);
      va[j] = fmaf(xn, Wv[d * 8 + j], va[j]);
    }
  }

  {
    float4* kp = (float4*)(kb + ((size_t)l * NN + n) * 8);
    float4* vp = (float4*)(vb + ((size_t)l * NN + n) * 8);
    kp[0] = make_float4(ka[0], ka[1], ka[2], ka[3]);
    kp[1] = make_float4(ka[4], ka[5], ka[6], ka[7]);
    vp[0] = make_float4(va[0], va[1], va[2], va[3]);
    vp[1] = make_float4(va[4], va[5], va[6], va[7]);
  }

  {
    const bool hi1 = (lane & 16) != 0;
#pragma unroll
    for (int k = 0; k < 32; ++k) {
      const float keep = hi1 ? X[k + 32] : X[k];
      const float send = hi1 ? X[k] : X[k + 32];
      X[k] = keep + __shfl_xor(send, 16);
    }
    const bool hi2 = (lane & 32) != 0;
#pragma unroll
    for (int k = 0; k < 16; ++k) {
      const float keep = hi2 ? X[k + 16] : X[k];
      const float send = hi2 ? X[k] : X[k + 16];
      X[k] = keep + __shfl_xor(send, 32);
    }
  }
  const int d0i = ((lane >> 4) & 1) * 32 + (lane >> 5) * 16;
#pragma unroll
  for (int k = 0; k < 16; ++k) xc[w][l_loc][d0i + k] = X[k];
  __syncthreads();

#pragma unroll
  for (int j = 0; j < 4; ++j) {
    const int c = t * 4 + j;
    const int ll = c >> 6, d = c & 63;
    const float sv = xc[0][ll][d] + xc[1][ll][d] + xc[2][ll][d] + xc[3][ll][d];
    xbarP[((size_t)(l0 + ll) * NCH + nc) * DD + d] = sv;
  }
}

// ---------------------------------------------------------------------------
// Kernel B: unchanged (writes obT[d][l]).
// ---------------------------------------------------------------------------
__global__ __launch_bounds__(512) void kB(
    const float* __restrict__ kb, const float* __restrict__ vb,
    const float* __restrict__ xbarP, const float* __restrict__ Wq,
    float* __restrict__ obT)
{
  __shared__ float xbL[DD];
  __shared__ float qs[DD];
  __shared__ float ks[NN * 9];
  __shared__ float vs[NN * 9];
  const int l = blockIdx.x;
  const int t = threadIdx.x;
  const int h = t >> 6;
  const int lane = t & 63;

  const float* kl = kb + (size_t)l * NN * 8;
  const float* vl = vb + (size_t)l * NN * 8;
#pragma unroll
  for (int i = 0; i < 8; ++i) {
    const int idx = i * 512 + t;
    const int n = idx >> 3, j = idx & 7;
    ks[n*9 + j] = kl[idx];
    vs[n*9 + j] = vl[idx];
  }
  if (t < DD) {
    float s = 0.f;
    for (int p = 0; p < NCH; ++p) s += xbarP[((size_t)l * NCH + p) * DD + t];
    xbL[t] = s * (1.f / NN);
  }
  __syncthreads();
  if (t < DD) {
    float acc = 0.f;
    for (int d = 0; d < DD; ++d) acc = fmaf(xbL[d], Wq[d*DD + t], acc);
    qs[t] = acc * 0.35355339059327373f;
  }
  __syncthreads();

  float sc[8];
  float m = -1e30f;
#pragma unroll
  for (int i = 0; i < 8; ++i) {
    const int n = i * 64 + lane;
    float s = 0.f;
#pragma unroll
    for (int d = 0; d < 8; ++d) s = fmaf(qs[h*8 + d], ks[n*9 + d], s);
    sc[i] = s;
    m = fmaxf(m, s);
  }
#pragma unroll
  for (int off = 32; off; off >>= 1) m = fmaxf(m, __shfl_xor(m, off));
  float ssum = 0.f;
#pragma unroll
  for (int i = 0; i < 8; ++i) { sc[i] = __expf(sc[i] - m); ssum += sc[i]; }
#pragma unroll
  for (int off = 32; off; off >>= 1) ssum += __shfl_xor(ssum, off);
  const float inv = 1.f / ssum;

  float oacc[8];
#pragma unroll
  for (int d = 0; d < 8; ++d) oacc[d] = 0.f;
#pragma unroll
  for (int i = 0; i < 8; ++i) {
    const int n = i * 64 + lane;
#pragma unroll
    for (int d = 0; d < 8; ++d) oacc[d] = fmaf(sc[i], vs[n*9 + d], oacc[d]);
  }
#pragma unroll
  for (int d = 0; d < 8; ++d) {
#pragma unroll
    for (int off = 32; off; off >>= 1) oacc[d] += __shfl_xor(oacc[d], off);
  }
  if (lane == 0) {
#pragma unroll
    for (int d = 0; d < 8; ++d)
      obT[(size_t)(h * 8 + d) * LL + l] = oacc[d] * inv;
  }
}

// ---------------------------------------------------------------------------
// Kernel C v7: mv1 A-frags built ON THE FLY from raw msa (f32, 2KB-contig
// per wave-load) + per-row stats (aa,bb) + lnw/lnb — no xnh buffer at all.
// 2-term mv1 -> sigmoid*o -> t hi/lo (wave-private LDS) -> 3-term mv2.
// Zero barriers. 128 rows/block, 4 waves.
// A-frag: lane holds row=(lane&15), k=8*(lane>>4)+e (+32 for second half).
// C/D: reg j -> row=(lane>>4)*4+j, col=lane&15.
// ---------------------------------------------------------------------------
__global__ __launch_bounds__(256, 4) void kC(
    const float* __restrict__ msa, const float* __restrict__ stats,
    const float* __restrict__ lnw, const float* __restrict__ lnb,
    const unsigned* __restrict__ Bpk, const float* __restrict__ bg,
    const float* __restrict__ obT, const float* __restrict__ bout,
    float* __restrict__ out)
{
  __shared__ unsigned short TH[128 * 72];  // 18 KB (t hi)
  __shared__ unsigned short TL[128 * 72];  // 18 KB (t lo)
  const int t = threadIdx.x;
  const int lane = t & 63;
  const int w = t >> 6;
  const int rbase = 32 * w;
  const size_t R0 = (size_t)blockIdx.x * 128;

  const short8* Bp = (const short8*)Bpk;   // frag*64 + lane

  f32x4 acc[2][4];
#pragma unroll
  for (int rt = 0; rt < 2; ++rt)
#pragma unroll
    for (int ct = 0; ct < 4; ++ct) acc[rt][ct] = f32x4{0.f, 0.f, 0.f, 0.f};

  // ---- mv1: A-frags from raw msa + stats (no staging buffer) ----
  {
    short8 ah[2][2];
#pragma unroll
    for (int rt = 0; rt < 2; ++rt) {
      const size_t ar = R0 + rbase + rt * 16 + (lane & 15);
      const int kg = (lane >> 4) * 8;
      const float2 ab = *(const float2*)&stats[ar * 2];
      const float aa = ab.x, bb = ab.y;
#pragma unroll
      for (int hh = 0; hh < 2; ++hh) {
        const int d0 = kg + hh * 32;
        const float4 f0 = *(const float4*)&msa[ar * DD + d0];
        const float4 f1 = *(const float4*)&msa[ar * DD + d0 + 4];
        const float4 w0 = *(const float4*)&lnw[d0];
        const float4 w1 = *(const float4*)&lnw[d0 + 4];
        const float4 b0 = *(const float4*)&lnb[d0];
        const float4 b1 = *(const float4*)&lnb[d0 + 4];
        const unsigned q0 = bf16_rne(fmaf(fmaf(f0.x, aa, bb), w0.x, b0.x)) |
                           (bf16_rne(fmaf(fmaf(f0.y, aa, bb), w0.y, b0.y)) << 16);
        const unsigned q1 = bf16_rne(fmaf(fmaf(f0.z, aa, bb), w0.z, b0.z)) |
                           (bf16_rne(fmaf(fmaf(f0.w, aa, bb), w0.w, b0.w)) << 16);
        const unsigned q2 = bf16_rne(fmaf(fmaf(f1.x, aa, bb), w1.x, b1.x)) |
                           (bf16_rne(fmaf(fmaf(f1.y, aa, bb), w1.y, b1.y)) << 16);
        const unsigned q3 = bf16_rne(fmaf(fmaf(f1.z, aa, bb), w1.z, b1.z)) |
                           (bf16_rne(fmaf(fmaf(f1.w, aa, bb), w1.w, b1.w)) << 16);
        ah[rt][hh] = pack8(q0, q1, q2, q3);
      }
    }
#pragma unroll
    for (int ct = 0; ct < 4; ++ct) {
      const short8 bh0 = Bp[(0 * 8 + ct * 2 + 0) * 64 + lane];
      const short8 bh1 = Bp[(0 * 8 + ct * 2 + 1) * 64 + lane];
      const short8 bl0 = Bp[(1 * 8 + ct * 2 + 0) * 64 + lane];
      const short8 bl1 = Bp[(1 * 8 + ct * 2 + 1) * 64 + lane];
#pragma unroll
      for (int rt = 0; rt < 2; ++rt) {
        f32x4 c = acc[rt][ct];
        c = __builtin_amdgcn_mfma_f32_16x16x32_bf16(ah[rt][0], bh0, c, 0, 0, 0);
        c = __builtin_amdgcn_mfma_f32_16x16x32_bf16(ah[rt][1], bh1, c, 0, 0, 0);
        c = __builtin_amdgcn_mfma_f32_16x16x32_bf16(ah[rt][0], bl0, c, 0, 0, 0);
        c = __builtin_amdgcn_mfma_f32_16x16x32_bf16(ah[rt][1], bl1, c, 0, 0, 0);
        acc[rt][ct] = c;
      }
    }
  }

  // ---- sigmoid * o -> t, pure-C hi/lo split into TH/TL (wave-private) ----
#pragma unroll
  for (int rt = 0; rt < 2; ++rt) {
    const int rl0 = rbase + rt * 16 + ((lane >> 4) << 2);
    const int li0 = (int)((R0 + rl0) & (LL - 1));
#pragma unroll
    for (int ct = 0; ct < 4; ++ct) {
      const int col = ct * 16 + (lane & 15);
      const float4 ov = *(const float4*)&obT[(size_t)col * LL + li0];
      const float bgc = bg[col];
#define SIG_STORE(j, ocomp)                                             \
      {                                                                 \
        const float pre = acc[rt][ct][j] + bgc;                         \
        const float tv = (ocomp) / (1.f + __expf(-pre));                \
        const unsigned hb = bf16_rne(tv);                               \
        TH[(rl0 + (j)) * 72 + col] = (unsigned short)hb;                \
        const float rvl = tv - __uint_as_float(hb << 16);               \
        TL[(rl0 + (j)) * 72 + col] = (unsigned short)bf16_rne(rvl);     \
      }
      SIG_STORE(0, ov.x) SIG_STORE(1, ov.y) SIG_STORE(2, ov.z) SIG_STORE(3, ov.w)
#undef SIG_STORE
    }
  }
  // no barrier: wave-private rows

  // ---- mv2: out = t @ Wout + bout (3-term) ----
#pragma unroll
  for (int rt = 0; rt < 2; ++rt)
#pragma unroll
    for (int ct = 0; ct < 4; ++ct) {
      const float bo = bout[ct * 16 + (lane & 15)];
      acc[rt][ct] = f32x4{bo, bo, bo, bo};
    }
  {
    short8 ah[2][2], al[2][2];
#pragma unroll
    for (int rt = 0; rt < 2; ++rt) {
      const int ar = rbase + rt * 16 + (lane & 15);
      const int kg = (lane >> 4) * 8;
      ah[rt][0] = *(const short8*)&TH[ar * 72 + kg];
      ah[rt][1] = *(const short8*)&TH[ar * 72 + 32 + kg];
      al[rt][0] = *(const short8*)&TL[ar * 72 + kg];
      al[rt][1] = *(const short8*)&TL[ar * 72 + 32 + kg];
    }
#pragma unroll
    for (int ct = 0; ct < 4; ++ct) {
      const short8 bh0 = Bp[(2 * 8 + ct * 2 + 0) * 64 + lane];
      const short8 bh1 = Bp[(2 * 8 + ct * 2 + 1) * 64 + lane];
      const short8 bl0 = Bp[(3 * 8 + ct * 2 + 0) * 64 + lane];
      const short8 bl1 = Bp[(3 * 8 + ct * 2 + 1) * 64 + lane];
#pragma unroll
      for (int rt = 0; rt < 2; ++rt) {
        f32x4 c = acc[rt][ct];
        c = __builtin_amdgcn_mfma_f32_16x16x32_bf16(ah[rt][0], bh0, c, 0, 0, 0);
        c = __builtin_amdgcn_mfma_f32_16x16x32_bf16(ah[rt][1], bh1, c, 0, 0, 0);
        c = __builtin_amdgcn_mfma_f32_16x16x32_bf16(ah[rt][0], bl0, c, 0, 0, 0);
        c = __builtin_amdgcn_mfma_f32_16x16x32_bf16(ah[rt][1], bl1, c, 0, 0, 0);
        c = __builtin_amdgcn_mfma_f32_16x16x32_bf16(al[rt][0], bh0, c, 0, 0, 0);
        c = __builtin_amdgcn_mfma_f32_16x16x32_bf16(al[rt][1], bh1, c, 0, 0, 0);
        acc[rt][ct] = c;
      }
    }
  }

#pragma unroll
  for (int rt = 0; rt < 2; ++rt) {
#pragma unroll
    for (int j = 0; j < 4; ++j) {
      const size_t rg = R0 + rbase + rt * 16 + ((lane >> 4) << 2) + j;
#pragma unroll
      for (int ct = 0; ct < 4; ++ct)
        out[rg * DD + ct * 16 + (lane & 15)] = acc[rt][ct][j];
    }
  }
}

// ---------------------------------------------------------------------------
extern "C" void kernel_launch(void* const* d_in, const int* in_sizes, int n_in,
                              void* d_out, int out_size, void* d_ws, size_t ws_size,
                              hipStream_t stream)
{
  const float* msa  = (const float*)d_in[0];
  const float* lnw  = (const float*)d_in[1];
  const float* lnb  = (const float*)d_in[2];
  const float* Wq   = (const float*)d_in[3];
  const float* Wk   = (const float*)d_in[4];
  const float* Wv   = (const float*)d_in[5];
  const float* Wg   = (const float*)d_in[6];
  const float* bg   = (const float*)d_in[7];
  const float* Wout = (const float*)d_in[8];
  const float* bout = (const float*)d_in[9];
  float* out = (float*)d_out;

  float* kb    = (float*)d_ws;                        // (L, N, 8)  16 MB
  float* vb    = kb + (size_t)LL * NN * 8;            // (L, N, 8)  16 MB
  float* xbarP = vb + (size_t)LL * NN * 8;            // (L, 32, 64) 8 MB
  float* obT   = xbarP + (size_t)LL * NCH * DD;       // (64, L)   256 KB
  unsigned* Bpk = (unsigned*)(obT + (size_t)DD * LL); // 32 KB packed weights
  float* stats = (float*)(Bpk + 8192);                // (N*L, 2)  4 MB

  kW<<<32, 256, 0, stream>>>(Wg, Wout, Bpk);
  kA<<<64 * NCH, 256, 0, stream>>>(msa, lnw, lnb, Wk, Wv, kb, vb, xbarP, stats);
  kB<<<LL, 512, 0, stream>>>(kb, vb, xbarP, Wq, obT);
  kC<<<(NN * LL) / 128, 256, 0, stream>>>(msa, stats, lnw, lnb, Bpk, bg, obT, bout, out);
}

// Round 13
// 121.080 us; speedup vs baseline: 1.3036x; 1.0395x over previous
//
#include <hip/hip_runtime.h>
#include <math.h>

#define DD 64
#define NN 512
#define LL 1024
#define EPSF 1e-5f
#define NCH 32   // n-chunks (xbar partials per l)

typedef short short8 __attribute__((ext_vector_type(8)));
typedef float f32x4 __attribute__((ext_vector_type(4)));

// pure-C round-to-nearest-even bf16 (bits in low 16) — NO inline asm
static __device__ __forceinline__ unsigned bf16_rne(float f) {
  unsigned u = __float_as_uint(f);
  return (u + 0x7FFFu + ((u >> 16) & 1u)) >> 16;
}
static __device__ __forceinline__ float bf16_hi_f(float f) {
  unsigned u = __float_as_uint(f);
  return __uint_as_float((u + 0x7FFFu + ((u >> 16) & 1u)) & 0xFFFF0000u);
}
static __device__ __forceinline__ short8 pack8(unsigned a, unsigned b,
                                               unsigned c, unsigned d) {
  union { uint4 u; short8 s; } x;
  x.u = make_uint4(a, b, c, d);
  return x.s;
}

// ---------------------------------------------------------------------------
// Kernel A (R12, proven): block = 16 l x 16 n rows; thread = one row in regs
// (X[64]); LN stats -> 8B stats store -> fused d-loop (xn, k/v FMAs) ->
// k/v store -> butterfly -> xbar partial. No wide bf16 store phase.
// ---------------------------------------------------------------------------
__global__ __launch_bounds__(256, 4) void kA(
    const float* __restrict__ msa, const float* __restrict__ lnw, const float* __restrict__ lnb,
    const float* __restrict__ Wk, const float* __restrict__ Wv,
    float* __restrict__ kb, float* __restrict__ vb, float* __restrict__ xbarP,
    float* __restrict__ stats)
{
  __shared__ float xc[4][16][68];
  const int t = threadIdx.x;
  const int lane = t & 63;
  const int w = t >> 6;
  const int l_loc = t & 15;
  const int n_loc = t >> 4;
  const int lt = blockIdx.x & 63;
  const int nc = blockIdx.x >> 6;
  const int l0 = lt * 16;
  const int n = nc * 16 + n_loc;
  const int l = l0 + l_loc;

  float X[DD];
  {
    const float4* rp = (const float4*)(msa + ((size_t)n * LL + l) * DD);
#pragma unroll
    for (int i = 0; i < 16; ++i) {
      const float4 f = rp[i];
      X[4*i+0] = f.x; X[4*i+1] = f.y; X[4*i+2] = f.z; X[4*i+3] = f.w;
    }
  }

  float s = 0.f, s2 = 0.f;
#pragma unroll
  for (int d = 0; d < DD; ++d) { s += X[d]; s2 = fmaf(X[d], X[d], s2); }
  const float mu = s * (1.f / DD);
  const float rs = rsqrtf(fmaf(-mu, mu, s2 * (1.f / DD)) + EPSF);

  {
    float2* sp = (float2*)(stats + ((size_t)n * LL + l) * 2);
    *sp = make_float2(rs, -mu * rs);
  }

  float ka[8], va[8];
#pragma unroll
  for (int j = 0; j < 8; ++j) { ka[j] = 0.f; va[j] = 0.f; }
#pragma unroll
  for (int d = 0; d < DD; ++d) {
    const float xn = fmaf((X[d] - mu) * rs, lnw[d], lnb[d]);
    X[d] = xn;
#pragma unroll
    for (int j = 0; j < 8; ++j) {
      ka[j] = fmaf(xn, Wk[d * 8 + j], ka[j]);
      va[j] = fmaf(xn, Wv[d * 8 + j], va[j]);
    }
  }

  {
    float4* kp = (float4*)(kb + ((size_t)l * NN + n) * 8);
    float4* vp = (float4*)(vb + ((size_t)l * NN + n) * 8);
    kp[0] = make_float4(ka[0], ka[1], ka[2], ka[3]);
    kp[1] = make_float4(ka[4], ka[5], ka[6], ka[7]);
    vp[0] = make_float4(va[0], va[1], va[2], va[3]);
    vp[1] = make_float4(va[4], va[5], va[6], va[7]);
  }

  {
    const bool hi1 = (lane & 16) != 0;
#pragma unroll
    for (int k = 0; k < 32; ++k) {
      const float keep = hi1 ? X[k + 32] : X[k];
      const float send = hi1 ? X[k] : X[k + 32];
      X[k] = keep + __shfl_xor(send, 16);
    }
    const bool hi2 = (lane & 32) != 0;
#pragma unroll
    for (int k = 0; k < 16; ++k) {
      const float keep = hi2 ? X[k + 16] : X[k];
      const float send = hi2 ? X[k] : X[k + 16];
      X[k] = keep + __shfl_xor(send, 32);
    }
  }
  const int d0i = ((lane >> 4) & 1) * 32 + (lane >> 5) * 16;
#pragma unroll
  for (int k = 0; k < 16; ++k) xc[w][l_loc][d0i + k] = X[k];
  __syncthreads();

#pragma unroll
  for (int j = 0; j < 4; ++j) {
    const int c = t * 4 + j;
    const int ll = c >> 6, d = c & 63;
    const float sv = xc[0][ll][d] + xc[1][ll][d] + xc[2][ll][d] + xc[3][ll][d];
    xbarP[((size_t)(l0 + ll) * NCH + nc) * DD + d] = sv;
  }
}

// ---------------------------------------------------------------------------
// Kernel B v2: (a) blocks 0-15 also perform the Wg/Wout MFMA-fragment pack
// (formerly kernel kW; Bpk consumed only by kC which runs after kB);
// (b) xbar reduction parallelized across all 8 waves (coalesced 256B rows).
// Then q = xbar@Wq, scores/softmax/PV per head-wave; writes obT[d][l].
// ---------------------------------------------------------------------------
__global__ __launch_bounds__(512) void kB(
    const float* __restrict__ kb, const float* __restrict__ vb,
    const float* __restrict__ xbarP, const float* __restrict__ Wq,
    const float* __restrict__ Wg, const float* __restrict__ Wout,
    unsigned* __restrict__ Bpk, float* __restrict__ obT)
{
  __shared__ float xbL[DD];
  __shared__ float qs[DD];
  __shared__ float red[8][68];
  __shared__ float ks[NN * 9];
  __shared__ float vs[NN * 9];
  const int l = blockIdx.x;
  const int t = threadIdx.x;
  const int h = t >> 6;          // wave id == head
  const int lane = t & 63;

  // ---- folded kW: pack Wg/Wout split-bf16 B-fragments (blocks 0..15) ----
  if (blockIdx.x < 16) {
    const int idx = blockIdx.x * 512 + t;   // 0..8191
    const int e2   = idx & 3;
    const int plane = (idx >> 2) & 63;
    const int ctkt = (idx >> 8) & 7;
    const int hh   = (idx >> 11) & 1;
    const int mv   = (idx >> 12) & 1;
    const int col  = ((ctkt >> 1) << 4) | (plane & 15);
    const int k0   = ((ctkt & 1) << 5) + ((plane >> 4) << 3) + (e2 << 1);
    const float* W = mv ? Wout : Wg;
    const float w0 = W[k0 * DD + col];
    const float w1 = W[(k0 + 1) * DD + col];
    unsigned b0, b1;
    if (hh == 0) { b0 = bf16_rne(w0); b1 = bf16_rne(w1); }
    else         { b0 = bf16_rne(w0 - bf16_hi_f(w0)); b1 = bf16_rne(w1 - bf16_hi_f(w1)); }
    Bpk[idx] = b0 | (b1 << 16);
  }

  // ---- k/v staging (unchanged) + parallel xbar reduce ----
  const float* kl = kb + (size_t)l * NN * 8;
  const float* vl = vb + (size_t)l * NN * 8;
#pragma unroll
  for (int i = 0; i < 8; ++i) {
    const int idx = i * 512 + t;
    const int n = idx >> 3, j = idx & 7;
    ks[n*9 + j] = kl[idx];
    vs[n*9 + j] = vl[idx];
  }
  {
    float sxb = 0.f;
#pragma unroll
    for (int i = 0; i < 4; ++i)
      sxb += xbarP[((size_t)l * NCH + (h + 8 * i)) * DD + lane];
    red[h][lane] = sxb;
  }
  __syncthreads();
  if (t < DD) {
    const float sv = ((red[0][t] + red[1][t]) + (red[2][t] + red[3][t]))
                   + ((red[4][t] + red[5][t]) + (red[6][t] + red[7][t]));
    xbL[t] = sv * (1.f / NN);
  }
  __syncthreads();
  if (t < DD) {
    float acc = 0.f;
    for (int d = 0; d < DD; ++d) acc = fmaf(xbL[d], Wq[d*DD + t], acc);
    qs[t] = acc * 0.35355339059327373f;   // 1/sqrt(DH)
  }
  __syncthreads();

  float sc[8];
  float m = -1e30f;
#pragma unroll
  for (int i = 0; i < 8; ++i) {
    const int n = i * 64 + lane;
    float s = 0.f;
#pragma unroll
    for (int d = 0; d < 8; ++d) s = fmaf(qs[h*8 + d], ks[n*9 + d], s);
    sc[i] = s;
    m = fmaxf(m, s);
  }
#pragma unroll
  for (int off = 32; off; off >>= 1) m = fmaxf(m, __shfl_xor(m, off));
  float ssum = 0.f;
#pragma unroll
  for (int i = 0; i < 8; ++i) { sc[i] = __expf(sc[i] - m); ssum += sc[i]; }
#pragma unroll
  for (int off = 32; off; off >>= 1) ssum += __shfl_xor(ssum, off);
  const float inv = 1.f / ssum;

  float oacc[8];
#pragma unroll
  for (int d = 0; d < 8; ++d) oacc[d] = 0.f;
#pragma unroll
  for (int i = 0; i < 8; ++i) {
    const int n = i * 64 + lane;
#pragma unroll
    for (int d = 0; d < 8; ++d) oacc[d] = fmaf(sc[i], vs[n*9 + d], oacc[d]);
  }
#pragma unroll
  for (int d = 0; d < 8; ++d) {
#pragma unroll
    for (int off = 32; off; off >>= 1) oacc[d] += __shfl_xor(oacc[d], off);
  }
  if (lane == 0) {
#pragma unroll
    for (int d = 0; d < 8; ++d)
      obT[(size_t)(h * 8 + d) * LL + l] = oacc[d] * inv;
  }
}

// ---------------------------------------------------------------------------
// Kernel C v7 (R12, proven): mv1 A-frags built on the fly from raw msa +
// per-row stats + lnw/lnb (no staging buffer). 2-term mv1 -> sigmoid*o ->
// t hi/lo (wave-private LDS) -> 3-term mv2. Zero barriers. 128 rows/block.
// A-frag: lane holds row=(lane&15), k=8*(lane>>4)+e (+32 second half).
// C/D: reg j -> row=(lane>>4)*4+j, col=lane&15.
// ---------------------------------------------------------------------------
__global__ __launch_bounds__(256, 4) void kC(
    const float* __restrict__ msa, const float* __restrict__ stats,
    const float* __restrict__ lnw, const float* __restrict__ lnb,
    const unsigned* __restrict__ Bpk, const float* __restrict__ bg,
    const float* __restrict__ obT, const float* __restrict__ bout,
    float* __restrict__ out)
{
  __shared__ unsigned short TH[128 * 72];  // 18 KB (t hi)
  __shared__ unsigned short TL[128 * 72];  // 18 KB (t lo)
  const int t = threadIdx.x;
  const int lane = t & 63;
  const int w = t >> 6;
  const int rbase = 32 * w;
  const size_t R0 = (size_t)blockIdx.x * 128;

  const short8* Bp = (const short8*)Bpk;   // frag*64 + lane

  f32x4 acc[2][4];
#pragma unroll
  for (int rt = 0; rt < 2; ++rt)
#pragma unroll
    for (int ct = 0; ct < 4; ++ct) acc[rt][ct] = f32x4{0.f, 0.f, 0.f, 0.f};

  // ---- mv1: A-frags from raw msa + stats ----
  {
    short8 ah[2][2];
#pragma unroll
    for (int rt = 0; rt < 2; ++rt) {
      const size_t ar = R0 + rbase + rt * 16 + (lane & 15);
      const int kg = (lane >> 4) * 8;
      const float2 ab = *(const float2*)&stats[ar * 2];
      const float aa = ab.x, bb = ab.y;
#pragma unroll
      for (int hh = 0; hh < 2; ++hh) {
        const int d0 = kg + hh * 32;
        const float4 f0 = *(const float4*)&msa[ar * DD + d0];
        const float4 f1 = *(const float4*)&msa[ar * DD + d0 + 4];
        const float4 w0 = *(const float4*)&lnw[d0];
        const float4 w1 = *(const float4*)&lnw[d0 + 4];
        const float4 b0 = *(const float4*)&lnb[d0];
        const float4 b1 = *(const float4*)&lnb[d0 + 4];
        const unsigned q0 = bf16_rne(fmaf(fmaf(f0.x, aa, bb), w0.x, b0.x)) |
                           (bf16_rne(fmaf(fmaf(f0.y, aa, bb), w0.y, b0.y)) << 16);
        const unsigned q1 = bf16_rne(fmaf(fmaf(f0.z, aa, bb), w0.z, b0.z)) |
                           (bf16_rne(fmaf(fmaf(f0.w, aa, bb), w0.w, b0.w)) << 16);
        const unsigned q2 = bf16_rne(fmaf(fmaf(f1.x, aa, bb), w1.x, b1.x)) |
                           (bf16_rne(fmaf(fmaf(f1.y, aa, bb), w1.y, b1.y)) << 16);
        const unsigned q3 = bf16_rne(fmaf(fmaf(f1.z, aa, bb), w1.z, b1.z)) |
                           (bf16_rne(fmaf(fmaf(f1.w, aa, bb), w1.w, b1.w)) << 16);
        ah[rt][hh] = pack8(q0, q1, q2, q3);
      }
    }
#pragma unroll
    for (int ct = 0; ct < 4; ++ct) {
      const short8 bh0 = Bp[(0 * 8 + ct * 2 + 0) * 64 + lane];
      const short8 bh1 = Bp[(0 * 8 + ct * 2 + 1) * 64 + lane];
      const short8 bl0 = Bp[(1 * 8 + ct * 2 + 0) * 64 + lane];
      const short8 bl1 = Bp[(1 * 8 + ct * 2 + 1) * 64 + lane];
#pragma unroll
      for (int rt = 0; rt < 2; ++rt) {
        f32x4 c = acc[rt][ct];
        c = __builtin_amdgcn_mfma_f32_16x16x32_bf16(ah[rt][0], bh0, c, 0, 0, 0);
        c = __builtin_amdgcn_mfma_f32_16x16x32_bf16(ah[rt][1], bh1, c, 0, 0, 0);
        c = __builtin_amdgcn_mfma_f32_16x16x32_bf16(ah[rt][0], bl0, c, 0, 0, 0);
        c = __builtin_amdgcn_mfma_f32_16x16x32_bf16(ah[rt][1], bl1, c, 0, 0, 0);
        acc[rt][ct] = c;
      }
    }
  }

  // ---- sigmoid * o -> t, pure-C hi/lo split into TH/TL (wave-private) ----
#pragma unroll
  for (int rt = 0; rt < 2; ++rt) {
    const int rl0 = rbase + rt * 16 + ((lane >> 4) << 2);
    const int li0 = (int)((R0 + rl0) & (LL - 1));
#pragma unroll
    for (int ct = 0; ct < 4; ++ct) {
      const int col = ct * 16 + (lane & 15);
      const float4 ov = *(const float4*)&obT[(size_t)col * LL + li0];
      const float bgc = bg[col];
#define SIG_STORE(j, ocomp)                                             \
      {                                                                 \
        const float pre = acc[rt][ct][j] + bgc;                         \
        const float tv = (ocomp) / (1.f + __expf(-pre));                \
        const unsigned hb = bf16_rne(tv);                               \
        TH[(rl0 + (j)) * 72 + col] = (unsigned short)hb;                \
        const float rvl = tv - __uint_as_float(hb << 16);               \
        TL[(rl0 + (j)) * 72 + col] = (unsigned short)bf16_rne(rvl);     \
      }
      SIG_STORE(0, ov.x) SIG_STORE(1, ov.y) SIG_STORE(2, ov.z) SIG_STORE(3, ov.w)
#undef SIG_STORE
    }
  }
  // no barrier: wave-private rows

  // ---- mv2: out = t @ Wout + bout (3-term) ----
#pragma unroll
  for (int rt = 0; rt < 2; ++rt)
#pragma unroll
    for (int ct = 0; ct < 4; ++ct) {
      const float bo = bout[ct * 16 + (lane & 15)];
      acc[rt][ct] = f32x4{bo, bo, bo, bo};
    }
  {
    short8 ah[2][2], al[2][2];
#pragma unroll
    for (int rt = 0; rt < 2; ++rt) {
      const int ar = rbase + rt * 16 + (lane & 15);
      const int kg = (lane >> 4) * 8;
      ah[rt][0] = *(const short8*)&TH[ar * 72 + kg];
      ah[rt][1] = *(const short8*)&TH[ar * 72 + 32 + kg];
      al[rt][0] = *(const short8*)&TL[ar * 72 + kg];
      al[rt][1] = *(const short8*)&TL[ar * 72 + 32 + kg];
    }
#pragma unroll
    for (int ct = 0; ct < 4; ++ct) {
      const short8 bh0 = Bp[(2 * 8 + ct * 2 + 0) * 64 + lane];
      const short8 bh1 = Bp[(2 * 8 + ct * 2 + 1) * 64 + lane];
      const short8 bl0 = Bp[(3 * 8 + ct * 2 + 0) * 64 + lane];
      const short8 bl1 = Bp[(3 * 8 + ct * 2 + 1) * 64 + lane];
#pragma unroll
      for (int rt = 0; rt < 2; ++rt) {
        f32x4 c = acc[rt][ct];
        c = __builtin_amdgcn_mfma_f32_16x16x32_bf16(ah[rt][0], bh0, c, 0, 0, 0);
        c = __builtin_amdgcn_mfma_f32_16x16x32_bf16(ah[rt][1], bh1, c, 0, 0, 0);
        c = __builtin_amdgcn_mfma_f32_16x16x32_bf16(ah[rt][0], bl0, c, 0, 0, 0);
        c = __builtin_amdgcn_mfma_f32_16x16x32_bf16(ah[rt][1], bl1, c, 0, 0, 0);
        c = __builtin_amdgcn_mfma_f32_16x16x32_bf16(al[rt][0], bh0, c, 0, 0, 0);
        c = __builtin_amdgcn_mfma_f32_16x16x32_bf16(al[rt][1], bh1, c, 0, 0, 0);
        acc[rt][ct] = c;
      }
    }
  }

#pragma unroll
  for (int rt = 0; rt < 2; ++rt) {
#pragma unroll
    for (int j = 0; j < 4; ++j) {
      const size_t rg = R0 + rbase + rt * 16 + ((lane >> 4) << 2) + j;
#pragma unroll
      for (int ct = 0; ct < 4; ++ct)
        out[rg * DD + ct * 16 + (lane & 15)] = acc[rt][ct][j];
    }
  }
}

// ---------------------------------------------------------------------------
extern "C" void kernel_launch(void* const* d_in, const int* in_sizes, int n_in,
                              void* d_out, int out_size, void* d_ws, size_t ws_size,
                              hipStream_t stream)
{
  const float* msa  = (const float*)d_in[0];
  const float* lnw  = (const float*)d_in[1];
  const float* lnb  = (const float*)d_in[2];
  const float* Wq   = (const float*)d_in[3];
  const float* Wk   = (const float*)d_in[4];
  const float* Wv   = (const float*)d_in[5];
  const float* Wg   = (const float*)d_in[6];
  const float* bg   = (const float*)d_in[7];
  const float* Wout = (const float*)d_in[8];
  const float* bout = (const float*)d_in[9];
  float* out = (float*)d_out;

  float* kb    = (float*)d_ws;                        // (L, N, 8)  16 MB
  float* vb    = kb + (size_t)LL * NN * 8;            // (L, N, 8)  16 MB
  float* xbarP = vb + (size_t)LL * NN * 8;            // (L, 32, 64) 8 MB
  float* obT   = xbarP + (size_t)LL * NCH * DD;       // (64, L)   256 KB
  unsigned* Bpk = (unsigned*)(obT + (size_t)DD * LL); // 32 KB packed weights
  float* stats = (float*)(Bpk + 8192);                // (N*L, 2)  4 MB

  kA<<<64 * NCH, 256, 0, stream>>>(msa, lnw, lnb, Wk, Wv, kb, vb, xbarP, stats);
  kB<<<LL, 512, 0, stream>>>(kb, vb, xbarP, Wq, Wg, Wout, Bpk, obT);
  kC<<<(NN * LL) / 128, 256, 0, stream>>>(msa, stats, lnw, lnb, Bpk, bg, obT, bout, out);
}